// Round 6
// baseline (161.358 us; speedup 1.0000x reference)
//
#include <hip/hip_runtime.h>

#define HH 2160
#define WW 3840
#define NPATCH 256
#define PSZ 128
#define HW_ (HH*WW)
#define FMSZ (NPATCH*PSZ*PSZ)

#define TW 256
#define TH 16
#define NBX (WW/TW)     // 15
#define NBY (HH/TH)     // 135
#define NB  (NBX*NBY)   // 2025

typedef float fx4 __attribute__((ext_vector_type(4)));

// ws layout: fm | coef | partial[13][NB]
#define COEF_OFF  ((size_t)FMSZ*4)
#define PART_OFF  (COEF_OFF + 64)

// ---------------- feather: separable 9-tap gaussian, zero-padded per patch ----------------
// grid (NPATCH, 4): each block computes 32 output rows with +-4 halo in LDS
__global__ __launch_bounds__(256) void feather_kernel(
        const float* __restrict__ mask, const int* __restrict__ pos_y,
        const int* __restrict__ pos_x, float* __restrict__ fm) {
    __shared__ float sm[40*PSZ];
    __shared__ float tp[40*PSZ];
    const int n = blockIdx.x;
    const int r0 = blockIdx.y * 32;
    const int y0 = pos_y[n], x0 = pos_x[n];
    float g[9]; float s = 0.f;
    #pragma unroll
    for (int k = 0; k < 9; ++k) { float xx = (k-4)*0.75f; g[k] = expf(-0.5f*xx*xx); s += g[k]; }
    const float inv = 1.f/s;
    #pragma unroll
    for (int k = 0; k < 9; ++k) g[k] *= inv;

    for (int idx = threadIdx.x; idx < 40*PSZ; idx += 256) {
        int l = idx >> 7, j = idx & 127;
        int r = r0 + l - 4;
        sm[idx] = ((unsigned)r < (unsigned)PSZ) ? mask[(y0+r)*WW + (x0+j)] : 0.f;
    }
    __syncthreads();
    for (int idx = threadIdx.x; idx < 40*PSZ; idx += 256) {
        int l = idx >> 7, j = idx & 127;
        float a = 0.f;
        #pragma unroll
        for (int d = -4; d <= 4; ++d) {
            int jj = j + d;
            if (jj >= 0 && jj < PSZ) a += sm[(l<<7)+jj]*g[d+4];
        }
        tp[idx] = a;
    }
    __syncthreads();
    float* o = fm + n*(PSZ*PSZ) + r0*PSZ;
    for (int idx = threadIdx.x; idx < 32*PSZ; idx += 256) {
        int i = idx >> 7, j = idx & 127;
        float a = 0.f;
        #pragma unroll
        for (int d = 0; d < 9; ++d) a += tp[((i+d)<<7)+j]*g[d];
        o[idx] = a;
    }
}

// ---------------- compose: per-pixel ordered fold (4 rows/thread) + stat partials ----------------
__global__ __launch_bounds__(256) void compose_kernel(
        const float* __restrict__ orig, const float* __restrict__ patches,
        const float* __restrict__ mask, const int* __restrict__ pos_y,
        const int* __restrict__ pos_x, const float* __restrict__ fm,
        float* __restrict__ out, float* __restrict__ partial) {
    __shared__ int ln[NPATCH];
    __shared__ int ly[NPATCH];
    __shared__ int lx[NPATCH];
    __shared__ unsigned long long wm[4];
    __shared__ float red[4][13];

    const int tid = threadIdx.x;
    const int lane = tid & 63;
    const int wid  = tid >> 6;
    const int tx0 = blockIdx.x * TW;
    const int ty0 = blockIdx.y * TH;

    // ordered (ascending n) list of patches overlapping this 256x16 tile
    {
        const int yn = pos_y[tid], xn = pos_x[tid];
        const bool cov = (yn < ty0 + TH) && (yn + PSZ > ty0) &&
                         (xn < tx0 + TW) && (xn + PSZ > tx0);
        unsigned long long b = __ballot(cov);
        if (lane == 0) wm[wid] = b;
        __syncthreads();
        if (cov) {
            int pos = __popcll(b & ((1ull << lane) - 1ull));
            for (int w = 0; w < wid; ++w) pos += __popcll(wm[w]);
            ln[pos] = tid; ly[pos] = yn; lx[pos] = xn;
        }
        __syncthreads();
    }
    const int cnt = __popcll(wm[0]) + __popcll(wm[1]) + __popcll(wm[2]) + __popcll(wm[3]);

    const int x0 = tx0 + lane * 4;          // this thread's pixel-quad column

    float a_cnt = 0.f;
    float so1x=0,so1y=0,so1z=0, so2x=0,so2y=0,so2z=0;
    float sf1x=0,sf1y=0,sf1z=0, sf2x=0,sf2y=0,sf2z=0;

    const fx4* __restrict__ mask4 = (const fx4*)mask;
    const fx4* __restrict__ orig4 = (const fx4*)orig;
    fx4* __restrict__ out4 = (fx4*)out;

    #pragma unroll
    for (int rr = 0; rr < 4; ++rr) {
        const int y = ty0 + wid * 4 + rr;
        const int q = (y*WW + x0) >> 2;
        const fx4 m = mask4[q];
        fx4 v0 = __builtin_nontemporal_load(&orig4[q]);
        fx4 v1 = __builtin_nontemporal_load(&orig4[(HW_ >> 2) + q]);
        fx4 v2 = __builtin_nontemporal_load(&orig4[((2*HW_) >> 2) + q]);

        const float nhx = 1.f-m.x, nhy = 1.f-m.y, nhz = 1.f-m.z, nhw = 1.f-m.w;
        a_cnt += nhx+nhy+nhz+nhw;
        so1x += v0.x*nhx+v0.y*nhy+v0.z*nhz+v0.w*nhw;
        so2x += v0.x*v0.x*nhx+v0.y*v0.y*nhy+v0.z*v0.z*nhz+v0.w*v0.w*nhw;
        so1y += v1.x*nhx+v1.y*nhy+v1.z*nhz+v1.w*nhw;
        so2y += v1.x*v1.x*nhx+v1.y*v1.y*nhy+v1.z*v1.z*nhz+v1.w*v1.w*nhw;
        so1z += v2.x*nhx+v2.y*nhy+v2.z*nhz+v2.w*nhw;
        so2z += v2.x*v2.x*nhx+v2.y*v2.y*nhy+v2.z*v2.z*nhz+v2.w*v2.w*nhw;

        for (int k = 0; k < cnt; ++k) {
            const int dy = y - ly[k];
            if ((unsigned)dy >= (unsigned)PSZ) continue;
            const int dx0 = x0 - lx[k];
            if (dx0 <= -4 || dx0 >= PSZ) continue;
            const int nn = ln[k];
            const int rowb = dy << 7;
            const float* __restrict__ fmp = fm + nn*(PSZ*PSZ) + rowb;
            const float* __restrict__ pp  = patches + nn*(3*PSZ*PSZ) + rowb;
            #define BLEND(J, MX) { \
                const int dx = dx0 + J; \
                if ((unsigned)dx < (unsigned)PSZ) { \
                    const float f = fmp[dx]; const float of = 1.f - f; \
                    v0.MX = v0.MX*of + pp[dx]*f; \
                    v1.MX = v1.MX*of + pp[dx + PSZ*PSZ]*f; \
                    v2.MX = v2.MX*of + pp[dx + 2*PSZ*PSZ]*f; \
                } }
            BLEND(0, x) BLEND(1, y) BLEND(2, z) BLEND(3, w)
            #undef BLEND
        }

        out4[q] = v0;
        out4[(HW_ >> 2) + q] = v1;
        out4[((2*HW_) >> 2) + q] = v2;

        sf1x += v0.x*nhx+v0.y*nhy+v0.z*nhz+v0.w*nhw;
        sf2x += v0.x*v0.x*nhx+v0.y*v0.y*nhy+v0.z*v0.z*nhz+v0.w*v0.w*nhw;
        sf1y += v1.x*nhx+v1.y*nhy+v1.z*nhz+v1.w*nhw;
        sf2y += v1.x*v1.x*nhx+v1.y*v1.y*nhy+v1.z*v1.z*nhz+v1.w*v1.w*nhw;
        sf1z += v2.x*nhx+v2.y*nhy+v2.z*nhz+v2.w*nhw;
        sf2z += v2.x*v2.x*nhx+v2.y*v2.y*nhy+v2.z*v2.z*nhz+v2.w*v2.w*nhw;
    }

    // --- tail: stats shuffle reduce, single barrier ---
    float vals[13] = {a_cnt, so1x,so1y,so1z, so2x,so2y,so2z,
                      sf1x,sf1y,sf1z, sf2x,sf2y,sf2z};
    #pragma unroll
    for (int v = 0; v < 13; ++v) {
        float t = vals[v];
        t += __shfl_down(t, 32); t += __shfl_down(t, 16);
        t += __shfl_down(t, 8);  t += __shfl_down(t, 4);
        t += __shfl_down(t, 2);  t += __shfl_down(t, 1);
        if (lane == 0) red[wid][v] = t;
    }
    __syncthreads();
    if (tid < 13) {
        const int bid = blockIdx.y * NBX + blockIdx.x;
        partial[tid*NB + bid] = red[0][tid] + red[1][tid] + red[2][tid] + red[3][tid];
    }
}

// ---------------- finalize: 13 waves, one per statistic; thread 0 emits coefs ----------------
__global__ __launch_bounds__(832) void finalize_kernel(
        const float* __restrict__ partial, float* __restrict__ coef) {
    __shared__ double tot[13];
    const int w = threadIdx.x >> 6;          // 0..12
    const int lane = threadIdx.x & 63;
    const float* p = partial + w*NB;
    double s0 = 0.0, s1 = 0.0;
    int b = lane;
    for (; b + 64 < NB; b += 128) { s0 += (double)p[b]; s1 += (double)p[b+64]; }
    if (b < NB) s0 += (double)p[b];
    double t = s0 + s1;
    t += __shfl_down(t, 32); t += __shfl_down(t, 16);
    t += __shfl_down(t, 8);  t += __shfl_down(t, 4);
    t += __shfl_down(t, 2);  t += __shfl_down(t, 1);
    if (lane == 0) tot[w] = t;
    __syncthreads();
    if (threadIdx.x == 0) {
        const double cnt = tot[0];
        for (int c = 0; c < 3; ++c) {
            double om = tot[1+c]/cnt;
            double ov = tot[4+c]/cnt - om*om;
            double os = sqrt(ov > 0.0 ? ov : 0.0);
            double fmn = tot[7+c]/cnt;
            double fv = tot[10+c]/cnt - fmn*fmn;
            double fs = sqrt(fv > 0.0 ? fv : 0.0);
            coef[c]   = (float)(os/(fs + 1e-8));
            coef[3+c] = (float)fmn;
            coef[6+c] = (float)om;
        }
    }
}

// ---------------- correct: mask-driven, quad early-out ----------------
__global__ __launch_bounds__(256) void correct_kernel(
        float* __restrict__ out, const float* __restrict__ mask,
        const float* __restrict__ coef) {
    const int q = blockIdx.x * 256 + threadIdx.x;
    if (q >= (HW_ >> 2)) return;
    const fx4 m = ((const fx4*)mask)[q];
    if (m.x == 0.f && m.y == 0.f && m.z == 0.f && m.w == 0.f) return;
    const float r0 = coef[0], r1 = coef[1], r2 = coef[2];
    const float f0 = coef[3], f1 = coef[4], f2 = coef[5];
    const float o0 = coef[6], o1 = coef[7], o2 = coef[8];
    fx4* __restrict__ out4 = (fx4*)out;
    fx4 v0 = out4[q];
    fx4 v1 = out4[(HW_>>2)+q];
    fx4 v2 = out4[((2*HW_)>>2)+q];
    if (m.x != 0.f) { v0.x=(v0.x-f0)*r0+o0; v1.x=(v1.x-f1)*r1+o1; v2.x=(v2.x-f2)*r2+o2; }
    if (m.y != 0.f) { v0.y=(v0.y-f0)*r0+o0; v1.y=(v1.y-f1)*r1+o1; v2.y=(v2.y-f2)*r2+o2; }
    if (m.z != 0.f) { v0.z=(v0.z-f0)*r0+o0; v1.z=(v1.z-f1)*r1+o1; v2.z=(v2.z-f2)*r2+o2; }
    if (m.w != 0.f) { v0.w=(v0.w-f0)*r0+o0; v1.w=(v1.w-f1)*r1+o1; v2.w=(v2.w-f2)*r2+o2; }
    out4[q] = v0;
    out4[(HW_>>2)+q] = v1;
    out4[((2*HW_)>>2)+q] = v2;
}

extern "C" void kernel_launch(void* const* d_in, const int* in_sizes, int n_in,
                              void* d_out, int out_size, void* d_ws, size_t ws_size,
                              hipStream_t stream) {
    const float* orig    = (const float*)d_in[0];
    const float* patches = (const float*)d_in[1];
    const float* mask    = (const float*)d_in[2];
    const int*   pos_y   = (const int*)d_in[3];
    const int*   pos_x   = (const int*)d_in[4];
    float* out = (float*)d_out;

    float* fm      = (float*)d_ws;
    float* coef    = (float*)((char*)d_ws + COEF_OFF);
    float* partial = (float*)((char*)d_ws + PART_OFF);

    dim3 fg(NPATCH, 4);
    feather_kernel<<<fg, 256, 0, stream>>>(mask, pos_y, pos_x, fm);
    dim3 g(NBX, NBY);
    compose_kernel<<<g, 256, 0, stream>>>(orig, patches, mask, pos_y, pos_x, fm,
                                          out, partial);
    finalize_kernel<<<1, 832, 0, stream>>>(partial, coef);
    correct_kernel<<<((HW_ >> 2) + 255)/256, 256, 0, stream>>>(out, mask, coef);
}

// Round 7
// 138.233 us; speedup vs baseline: 1.1673x; 1.1673x over previous
//
#include <hip/hip_runtime.h>

#define HH 2160
#define WW 3840
#define NPATCH 256
#define PSZ 128
#define HW_ (HH*WW)
#define FMSZ (NPATCH*PSZ*PSZ)

#define TW 256
#define TH 8
#define NBX (WW/TW)     // 15
#define NBY (HH/TH)     // 270
#define NB  (NBX*NBY)   // 4050

typedef float fx4 __attribute__((ext_vector_type(4)));

// ws layout: fm | coef | partial[13][NB]
#define COEF_OFF  ((size_t)FMSZ*4)
#define PART_OFF  (COEF_OFF + 64)

// ---------------- feather: separable 9-tap gaussian, zero-padded per patch ----------------
// grid (NPATCH, 4): each block computes 32 output rows with +-4 halo in LDS
__global__ __launch_bounds__(256) void feather_kernel(
        const float* __restrict__ mask, const int* __restrict__ pos_y,
        const int* __restrict__ pos_x, float* __restrict__ fm) {
    __shared__ float sm[40*PSZ];
    __shared__ float tp[40*PSZ];
    const int n = blockIdx.x;
    const int r0 = blockIdx.y * 32;
    const int y0 = pos_y[n], x0 = pos_x[n];
    float g[9]; float s = 0.f;
    #pragma unroll
    for (int k = 0; k < 9; ++k) { float xx = (k-4)*0.75f; g[k] = expf(-0.5f*xx*xx); s += g[k]; }
    const float inv = 1.f/s;
    #pragma unroll
    for (int k = 0; k < 9; ++k) g[k] *= inv;

    for (int idx = threadIdx.x; idx < 40*PSZ; idx += 256) {
        int l = idx >> 7, j = idx & 127;
        int r = r0 + l - 4;
        sm[idx] = ((unsigned)r < (unsigned)PSZ) ? mask[(y0+r)*WW + (x0+j)] : 0.f;
    }
    __syncthreads();
    for (int idx = threadIdx.x; idx < 40*PSZ; idx += 256) {
        int l = idx >> 7, j = idx & 127;
        float a = 0.f;
        #pragma unroll
        for (int d = -4; d <= 4; ++d) {
            int jj = j + d;
            if (jj >= 0 && jj < PSZ) a += sm[(l<<7)+jj]*g[d+4];
        }
        tp[idx] = a;
    }
    __syncthreads();
    float* o = fm + n*(PSZ*PSZ) + r0*PSZ;
    for (int idx = threadIdx.x; idx < 32*PSZ; idx += 256) {
        int i = idx >> 7, j = idx & 127;
        float a = 0.f;
        #pragma unroll
        for (int d = 0; d < 9; ++d) a += tp[((i+d)<<7)+j]*g[d];
        o[idx] = a;
    }
}

// ---------------- compose: 512 threads, 1 row-quad per thread ----------------
__global__ __launch_bounds__(512) void compose_kernel(
        const float* __restrict__ orig, const float* __restrict__ patches,
        const float* __restrict__ mask, const int* __restrict__ pos_y,
        const int* __restrict__ pos_x, const float* __restrict__ fm,
        float* __restrict__ out, float* __restrict__ partial) {
    __shared__ int ln[NPATCH];
    __shared__ int ly[NPATCH];
    __shared__ int lx[NPATCH];
    __shared__ unsigned long long wm[4];
    __shared__ float red[8][13];

    const int tid = threadIdx.x;
    const int lane = tid & 63;
    const int wid  = tid >> 6;              // 0..7 = row within tile
    const int tx0 = blockIdx.x * TW;
    const int ty0 = blockIdx.y * TH;

    // ordered (ascending n) list of patches overlapping this 256x8 tile (waves 0-3)
    if (tid < NPATCH) {
        const int yn = pos_y[tid], xn = pos_x[tid];
        const bool cov = (yn < ty0 + TH) && (yn + PSZ > ty0) &&
                         (xn < tx0 + TW) && (xn + PSZ > tx0);
        unsigned long long b = __ballot(cov);
        if (lane == 0) wm[wid] = b;
        __syncthreads();
        if (cov) {
            int pos = __popcll(b & ((1ull << lane) - 1ull));
            for (int w = 0; w < wid; ++w) pos += __popcll(wm[w]);
            ln[pos] = tid; ly[pos] = yn; lx[pos] = xn;
        }
    } else {
        __syncthreads();
    }
    __syncthreads();
    const int cnt = __popcll(wm[0]) + __popcll(wm[1]) + __popcll(wm[2]) + __popcll(wm[3]);

    const int x0 = tx0 + lane * 4;          // this thread's pixel quad
    const int y  = ty0 + wid;               // this thread's row

    const fx4* __restrict__ mask4 = (const fx4*)mask;
    const fx4* __restrict__ orig4 = (const fx4*)orig;
    fx4* __restrict__ out4 = (fx4*)out;

    const int q = (y*WW + x0) >> 2;
    const fx4 m = mask4[q];
    fx4 v0 = __builtin_nontemporal_load(&orig4[q]);
    fx4 v1 = __builtin_nontemporal_load(&orig4[(HW_ >> 2) + q]);
    fx4 v2 = __builtin_nontemporal_load(&orig4[((2*HW_) >> 2) + q]);

    const float nhx = 1.f-m.x, nhy = 1.f-m.y, nhz = 1.f-m.z, nhw = 1.f-m.w;
    const float a_cnt = nhx+nhy+nhz+nhw;
    const float so1x = v0.x*nhx+v0.y*nhy+v0.z*nhz+v0.w*nhw;
    const float so2x = v0.x*v0.x*nhx+v0.y*v0.y*nhy+v0.z*v0.z*nhz+v0.w*v0.w*nhw;
    const float so1y = v1.x*nhx+v1.y*nhy+v1.z*nhz+v1.w*nhw;
    const float so2y = v1.x*v1.x*nhx+v1.y*v1.y*nhy+v1.z*v1.z*nhz+v1.w*v1.w*nhw;
    const float so1z = v2.x*nhx+v2.y*nhy+v2.z*nhz+v2.w*nhw;
    const float so2z = v2.x*v2.x*nhx+v2.y*v2.y*nhy+v2.z*v2.z*nhz+v2.w*v2.w*nhw;

    for (int k = 0; k < cnt; ++k) {
        const int dy = y - ly[k];
        if ((unsigned)dy >= (unsigned)PSZ) continue;
        const int dx0 = x0 - lx[k];
        if (dx0 <= -4 || dx0 >= PSZ) continue;
        const int nn = ln[k];
        const int rowb = dy << 7;
        const float* __restrict__ fmp = fm + nn*(PSZ*PSZ) + rowb;
        const float* __restrict__ pp  = patches + nn*(3*PSZ*PSZ) + rowb;
        #define BLEND(J, MX) { \
            const int dx = dx0 + J; \
            if ((unsigned)dx < (unsigned)PSZ) { \
                const float f = fmp[dx]; const float of = 1.f - f; \
                v0.MX = v0.MX*of + pp[dx]*f; \
                v1.MX = v1.MX*of + pp[dx + PSZ*PSZ]*f; \
                v2.MX = v2.MX*of + pp[dx + 2*PSZ*PSZ]*f; \
            } }
        BLEND(0, x) BLEND(1, y) BLEND(2, z) BLEND(3, w)
        #undef BLEND
    }

    out4[q] = v0;
    out4[(HW_ >> 2) + q] = v1;
    out4[((2*HW_) >> 2) + q] = v2;

    const float sf1x = v0.x*nhx+v0.y*nhy+v0.z*nhz+v0.w*nhw;
    const float sf2x = v0.x*v0.x*nhx+v0.y*v0.y*nhy+v0.z*v0.z*nhz+v0.w*v0.w*nhw;
    const float sf1y = v1.x*nhx+v1.y*nhy+v1.z*nhz+v1.w*nhw;
    const float sf2y = v1.x*v1.x*nhx+v1.y*v1.y*nhy+v1.z*v1.z*nhz+v1.w*v1.w*nhw;
    const float sf1z = v2.x*nhx+v2.y*nhy+v2.z*nhz+v2.w*nhw;
    const float sf2z = v2.x*v2.x*nhx+v2.y*v2.y*nhy+v2.z*v2.z*nhz+v2.w*v2.w*nhw;

    // --- tail: stats shuffle reduce, single barrier ---
    float vals[13] = {a_cnt, so1x,so1y,so1z, so2x,so2y,so2z,
                      sf1x,sf1y,sf1z, sf2x,sf2y,sf2z};
    #pragma unroll
    for (int v = 0; v < 13; ++v) {
        float t = vals[v];
        t += __shfl_down(t, 32); t += __shfl_down(t, 16);
        t += __shfl_down(t, 8);  t += __shfl_down(t, 4);
        t += __shfl_down(t, 2);  t += __shfl_down(t, 1);
        if (lane == 0) red[wid][v] = t;
    }
    __syncthreads();
    if (tid < 13) {
        const int bid = blockIdx.y * NBX + blockIdx.x;
        float sgl = 0.f;
        #pragma unroll
        for (int w = 0; w < 8; ++w) sgl += red[w][tid];
        partial[tid*NB + bid] = sgl;
    }
}

// ---------------- finalize: 13 waves, one per statistic; thread 0 emits coefs ----------------
__global__ __launch_bounds__(832) void finalize_kernel(
        const float* __restrict__ partial, float* __restrict__ coef) {
    __shared__ double tot[13];
    const int w = threadIdx.x >> 6;          // 0..12
    const int lane = threadIdx.x & 63;
    const float* p = partial + w*NB;
    double s0 = 0.0, s1 = 0.0;
    int b = lane;
    for (; b + 64 < NB; b += 128) { s0 += (double)p[b]; s1 += (double)p[b+64]; }
    if (b < NB) s0 += (double)p[b];
    double t = s0 + s1;
    t += __shfl_down(t, 32); t += __shfl_down(t, 16);
    t += __shfl_down(t, 8);  t += __shfl_down(t, 4);
    t += __shfl_down(t, 2);  t += __shfl_down(t, 1);
    if (lane == 0) tot[w] = t;
    __syncthreads();
    if (threadIdx.x == 0) {
        const double cnt = tot[0];
        for (int c = 0; c < 3; ++c) {
            double om = tot[1+c]/cnt;
            double ov = tot[4+c]/cnt - om*om;
            double os = sqrt(ov > 0.0 ? ov : 0.0);
            double fmn = tot[7+c]/cnt;
            double fv = tot[10+c]/cnt - fmn*fmn;
            double fs = sqrt(fv > 0.0 ? fv : 0.0);
            coef[c]   = (float)(os/(fs + 1e-8));
            coef[3+c] = (float)fmn;
            coef[6+c] = (float)om;
        }
    }
}

// ---------------- correct: mask-driven, quad early-out ----------------
__global__ __launch_bounds__(256) void correct_kernel(
        float* __restrict__ out, const float* __restrict__ mask,
        const float* __restrict__ coef) {
    const int q = blockIdx.x * 256 + threadIdx.x;
    if (q >= (HW_ >> 2)) return;
    const fx4 m = ((const fx4*)mask)[q];
    if (m.x == 0.f && m.y == 0.f && m.z == 0.f && m.w == 0.f) return;
    const float r0 = coef[0], r1 = coef[1], r2 = coef[2];
    const float f0 = coef[3], f1 = coef[4], f2 = coef[5];
    const float o0 = coef[6], o1 = coef[7], o2 = coef[8];
    fx4* __restrict__ out4 = (fx4*)out;
    fx4 v0 = out4[q];
    fx4 v1 = out4[(HW_>>2)+q];
    fx4 v2 = out4[((2*HW_)>>2)+q];
    if (m.x != 0.f) { v0.x=(v0.x-f0)*r0+o0; v1.x=(v1.x-f1)*r1+o1; v2.x=(v2.x-f2)*r2+o2; }
    if (m.y != 0.f) { v0.y=(v0.y-f0)*r0+o0; v1.y=(v1.y-f1)*r1+o1; v2.y=(v2.y-f2)*r2+o2; }
    if (m.z != 0.f) { v0.z=(v0.z-f0)*r0+o0; v1.z=(v1.z-f1)*r1+o1; v2.z=(v2.z-f2)*r2+o2; }
    if (m.w != 0.f) { v0.w=(v0.w-f0)*r0+o0; v1.w=(v1.w-f1)*r1+o1; v2.w=(v2.w-f2)*r2+o2; }
    out4[q] = v0;
    out4[(HW_>>2)+q] = v1;
    out4[((2*HW_)>>2)+q] = v2;
}

extern "C" void kernel_launch(void* const* d_in, const int* in_sizes, int n_in,
                              void* d_out, int out_size, void* d_ws, size_t ws_size,
                              hipStream_t stream) {
    const float* orig    = (const float*)d_in[0];
    const float* patches = (const float*)d_in[1];
    const float* mask    = (const float*)d_in[2];
    const int*   pos_y   = (const int*)d_in[3];
    const int*   pos_x   = (const int*)d_in[4];
    float* out = (float*)d_out;

    float* fm      = (float*)d_ws;
    float* coef    = (float*)((char*)d_ws + COEF_OFF);
    float* partial = (float*)((char*)d_ws + PART_OFF);

    dim3 fg(NPATCH, 4);
    feather_kernel<<<fg, 256, 0, stream>>>(mask, pos_y, pos_x, fm);
    dim3 g(NBX, NBY);
    compose_kernel<<<g, 512, 0, stream>>>(orig, patches, mask, pos_y, pos_x, fm,
                                          out, partial);
    finalize_kernel<<<1, 832, 0, stream>>>(partial, coef);
    correct_kernel<<<((HW_ >> 2) + 255)/256, 256, 0, stream>>>(out, mask, coef);
}